// Round 2
// baseline (423.453 us; speedup 1.0000x reference)
//
#include <hip/hip_runtime.h>

// RNN-T loss forward: B=8, T=128, U=100, V=1024, BLANK=0.
// out = mean over batch of -( alpha[tl-2, ul] + blank_lp[tl-2, ul] )

#define NEGV (-1e30f)

constexpr int Bb = 8;
constexpr int Tt = 128;
constexpr int Uu = 100;
constexpr int Vv = 1024;
constexpr int UP1 = Uu + 1;

__device__ __forceinline__ float laddexp(float x, float y) {
    float m = fmaxf(x, y);
    float d = fabsf(x - y);
    return m + log1pf(__expf(-d));
}

// Kernel 1: per (b,t,u) row of V=1024 logits, compute lse and emit the two
// log-probs we need. One wave (64 lanes) per row, 4 waves per block.
__global__ __launch_bounds__(256) void lse_kernel(
        const float* __restrict__ logits,
        const int*   __restrict__ targets,
        float* __restrict__ blank_lp,
        float* __restrict__ emit_lp) {
    const int wid  = blockIdx.x * 4 + (threadIdx.x >> 6);   // row index
    const int lane = threadIdx.x & 63;
    const int b   = wid / (Tt * UP1);
    const int rem = wid - b * (Tt * UP1);
    const int t   = rem / UP1;
    const int u   = rem - t * UP1;

    const float* row = logits + (size_t)wid * Vv;
    const float4* r4 = (const float4*)row;
    float4 x0 = r4[lane];
    float4 x1 = r4[lane + 64];
    float4 x2 = r4[lane + 128];
    float4 x3 = r4[lane + 192];

    float m = fmaxf(fmaxf(fmaxf(x0.x, x0.y), fmaxf(x0.z, x0.w)),
                    fmaxf(fmaxf(x1.x, x1.y), fmaxf(x1.z, x1.w)));
    m = fmaxf(m, fmaxf(fmaxf(fmaxf(x2.x, x2.y), fmaxf(x2.z, x2.w)),
                       fmaxf(fmaxf(x3.x, x3.y), fmaxf(x3.z, x3.w))));
    #pragma unroll
    for (int d = 32; d > 0; d >>= 1) m = fmaxf(m, __shfl_xor(m, d, 64));

    float s = __expf(x0.x - m) + __expf(x0.y - m) + __expf(x0.z - m) + __expf(x0.w - m)
            + __expf(x1.x - m) + __expf(x1.y - m) + __expf(x1.z - m) + __expf(x1.w - m)
            + __expf(x2.x - m) + __expf(x2.y - m) + __expf(x2.z - m) + __expf(x2.w - m)
            + __expf(x3.x - m) + __expf(x3.y - m) + __expf(x3.z - m) + __expf(x3.w - m);
    #pragma unroll
    for (int d = 32; d > 0; d >>= 1) s += __shfl_xor(s, d, 64);

    float lse = m + __logf(s);

    if (lane == 0) {
        blank_lp[wid] = x0.x - lse;             // x0.x of lane 0 == row[0] (BLANK)
        if (u < Uu) {
            int tgt = targets[b * Uu + u];
            emit_lp[(b * Tt + t) * Uu + u] = row[tgt] - lse;  // L1/L2 hit
        }
    }
}

// Kernel 2: per-batch DP. One block (64 lanes) per batch element; each lane
// owns u = 2*lane and 2*lane+1 of the alpha row. Scan combine:
//   combine((a1,c1),(a2,c2)) = (a1+a2, logaddexp(c2, c1+a2))
__global__ __launch_bounds__(64) void dp_kernel(
        const float* __restrict__ blank_lp,
        const float* __restrict__ emit_lp,
        const int*   __restrict__ logit_lengths,
        const int*   __restrict__ target_lengths,
        float* __restrict__ nll) {
    const int b    = blockIdx.x;
    const int lane = threadIdx.x;
    const float* blp = blank_lp + b * Tt * UP1;
    const float* elp = emit_lp  + b * Tt * Uu;
    const int tl = logit_lengths[b];
    const int ul = target_lengths[b];
    const int t_idx = tl - 2;   // reference: alpha[(tl-1)-1, ul]

    const int u0 = lane * 2, u1 = u0 + 1;
    const bool v0 = (u0 <= Uu), v1 = (u1 <= Uu);

    // alpha0: inclusive additive scan of h, h[0]=0, h[u]=emit[0][u-1]
    float h0 = (v0 && u0 > 0) ? elp[u0 - 1] : 0.0f;
    float h1 = v1 ? elp[u1 - 1] : 0.0f;
    float ssum = h0 + h1;
    #pragma unroll
    for (int d = 1; d < 64; d <<= 1) {
        float o = __shfl_up(ssum, d, 64);
        if (lane >= d) ssum += o;
    }
    float excl = __shfl_up(ssum, 1, 64);
    if (lane == 0) excl = 0.0f;
    float rc0 = excl + h0;       // alpha[0][u0]
    float rc1 = excl + h0 + h1;  // alpha[0][u1]

    float cap = NEGV;
    if (t_idx == 0) {
        float w0 = __shfl(rc0, ul >> 1, 64);
        float w1 = __shfl(rc1, ul >> 1, 64);
        cap = (ul & 1) ? w1 : w0;
    }

    for (int t = 1; t <= t_idx; ++t) {
        float c0 = v0 ? rc0 + blp[(t - 1) * UP1 + u0] : NEGV;
        float c1 = v1 ? rc1 + blp[(t - 1) * UP1 + u1] : NEGV;
        float a0;
        if (u0 == 0)      a0 = NEGV;
        else if (v0)      a0 = elp[t * Uu + u0 - 1];
        else              a0 = 0.0f;
        float a1 = v1 ? elp[t * Uu + u1 - 1] : 0.0f;

        // combine the lane's pair: left=(a0,c0), right=(a1,c1)
        float sa = a0 + a1;
        float sc = laddexp(c1, c0 + a1);

        // inclusive wave scan over lane aggregates (non-commutative combine)
        #pragma unroll
        for (int d = 1; d < 64; d <<= 1) {
            float oa = __shfl_up(sa, d, 64);
            float oc = __shfl_up(sc, d, 64);
            if (lane >= d) {
                float na = oa + sa;
                float nc = laddexp(sc, oc + sa);
                sa = na; sc = nc;
            }
        }
        // exclusive prefix for this lane
        float xc = __shfl_up(sc, 1, 64);
        if (lane == 0) xc = NEGV;

        rc1 = sc;                      // alpha[t][u1]
        rc0 = laddexp(c0, xc + a0);    // alpha[t][u0]

        if (t == t_idx) {
            float w0 = __shfl(rc0, ul >> 1, 64);
            float w1 = __shfl(rc1, ul >> 1, 64);
            cap = (ul & 1) ? w1 : w0;
        }
    }

    if (lane == 0) {
        float ll = cap + blp[t_idx * UP1 + ul];
        nll[b] = -ll;
    }
}

__global__ void mean_kernel(const float* __restrict__ nll, float* __restrict__ out) {
    if (threadIdx.x == 0 && blockIdx.x == 0) {
        float s = 0.0f;
        for (int i = 0; i < Bb; ++i) s += nll[i];
        out[0] = s / (float)Bb;
    }
}

extern "C" void kernel_launch(void* const* d_in, const int* in_sizes, int n_in,
                              void* d_out, int out_size, void* d_ws, size_t ws_size,
                              hipStream_t stream) {
    const float* logits        = (const float*)d_in[0];
    const int*   targets       = (const int*)d_in[1];
    const int*   logit_lengths = (const int*)d_in[2];
    const int*   target_lengths= (const int*)d_in[3];
    float* out = (float*)d_out;

    float* ws       = (float*)d_ws;
    float* blank_lp = ws;                              // B*T*(U+1) = 103424
    float* emit_lp  = blank_lp + Bb * Tt * UP1;        // B*T*U     = 102400
    float* nll      = emit_lp  + Bb * Tt * Uu;         // B         = 8

    const int rows = Bb * Tt * UP1;                    // 103424, divisible by 4
    lse_kernel<<<rows / 4, 256, 0, stream>>>(logits, targets, blank_lp, emit_lp);
    dp_kernel<<<Bb, 64, 0, stream>>>(blank_lp, emit_lp, logit_lengths, target_lengths, nll);
    mean_kernel<<<1, 64, 0, stream>>>(nll, out);
}

// Round 3
// 169.915 us; speedup vs baseline: 2.4921x; 2.4921x over previous
//
#include <hip/hip_runtime.h>

// RNN-T loss forward: B=8, T=128, U=100, V=1024, BLANK=0.
// out = mean over batch of -( alpha[tl-2, ul] + blank_lp[tl-2, ul] )

#define NEGV (-1e30f)

constexpr int Bb = 8;
constexpr int Tt = 128;
constexpr int Uu = 100;
constexpr int Vv = 1024;
constexpr int UP1 = Uu + 1;

__device__ __forceinline__ float laddexp(float x, float y) {
    float m = fmaxf(x, y);
    float d = fabsf(x - y);
    return m + __logf(1.0f + __expf(-d));
}

// ---- DPP wave64 scan primitives (VALU latency, no LDS) -------------------
// add-scan: invalid/masked lanes contribute 0 (old=0, bound_ctrl=true)
#define DPP_ADDSTEP(x, ctrl, rmask)                                          \
    x += __builtin_bit_cast(float, __builtin_amdgcn_update_dpp(              \
        0, __builtin_bit_cast(int, x), ctrl, rmask, 0xf, true))

#define WAVE_SCAN_ADD(x)           \
    DPP_ADDSTEP(x, 0x111, 0xf);    \
    DPP_ADDSTEP(x, 0x112, 0xf);    \
    DPP_ADDSTEP(x, 0x114, 0xf);    \
    DPP_ADDSTEP(x, 0x118, 0xf);    \
    DPP_ADDSTEP(x, 0x142, 0xa);    \
    DPP_ADDSTEP(x, 0x143, 0xc)

// max-scan: invalid/masked lanes keep own value (old=x, bound_ctrl=false)
#define DPP_MAXSTEP(x, ctrl, rmask) {                                        \
    float _t = __builtin_bit_cast(float, __builtin_amdgcn_update_dpp(        \
        __builtin_bit_cast(int, x), __builtin_bit_cast(int, x),              \
        ctrl, rmask, 0xf, false));                                           \
    x = fmaxf(x, _t); }

#define WAVE_SCAN_MAX(x)           \
    DPP_MAXSTEP(x, 0x111, 0xf);    \
    DPP_MAXSTEP(x, 0x112, 0xf);    \
    DPP_MAXSTEP(x, 0x114, 0xf);    \
    DPP_MAXSTEP(x, 0x118, 0xf);    \
    DPP_MAXSTEP(x, 0x142, 0xa);    \
    DPP_MAXSTEP(x, 0x143, 0xc)

__device__ __forceinline__ float readlane_f(float x, int lane) {
    return __builtin_bit_cast(float,
        __builtin_amdgcn_readlane(__builtin_bit_cast(int, x), lane));
}

// Kernel 1: per (b,t,u) row of V=1024 logits, compute lse and emit the two
// log-probs we need. One wave (64 lanes) per row, 4 waves per block.
__global__ __launch_bounds__(256) void lse_kernel(
        const float* __restrict__ logits,
        const int*   __restrict__ targets,
        float* __restrict__ blank_lp,
        float* __restrict__ emit_lp) {
    const int wid  = blockIdx.x * 4 + (threadIdx.x >> 6);   // row index
    const int lane = threadIdx.x & 63;
    const int b   = wid / (Tt * UP1);
    const int rem = wid - b * (Tt * UP1);
    const int t   = rem / UP1;
    const int u   = rem - t * UP1;

    const float* row = logits + (size_t)wid * Vv;
    const float4* r4 = (const float4*)row;
    float4 x0 = r4[lane];
    float4 x1 = r4[lane + 64];
    float4 x2 = r4[lane + 128];
    float4 x3 = r4[lane + 192];

    float m = fmaxf(fmaxf(fmaxf(x0.x, x0.y), fmaxf(x0.z, x0.w)),
                    fmaxf(fmaxf(x1.x, x1.y), fmaxf(x1.z, x1.w)));
    m = fmaxf(m, fmaxf(fmaxf(fmaxf(x2.x, x2.y), fmaxf(x2.z, x2.w)),
                       fmaxf(fmaxf(x3.x, x3.y), fmaxf(x3.z, x3.w))));
    #pragma unroll
    for (int d = 32; d > 0; d >>= 1) m = fmaxf(m, __shfl_xor(m, d, 64));

    float s = __expf(x0.x - m) + __expf(x0.y - m) + __expf(x0.z - m) + __expf(x0.w - m)
            + __expf(x1.x - m) + __expf(x1.y - m) + __expf(x1.z - m) + __expf(x1.w - m)
            + __expf(x2.x - m) + __expf(x2.y - m) + __expf(x2.z - m) + __expf(x2.w - m)
            + __expf(x3.x - m) + __expf(x3.y - m) + __expf(x3.z - m) + __expf(x3.w - m);
    #pragma unroll
    for (int d = 32; d > 0; d >>= 1) s += __shfl_xor(s, d, 64);

    float lse = m + __logf(s);

    if (lane == 0) {
        blank_lp[wid] = x0.x - lse;             // x0.x of lane 0 == row[0] (BLANK)
        if (u < Uu) {
            int tgt = targets[b * Uu + u];
            emit_lp[(b * Tt + t) * Uu + u] = row[tgt] - lse;  // L1/L2 hit
        }
    }
}

// Kernel 2: per-batch DP, one 64-lane wave per batch element. Lane owns
// u = 2*lane, 2*lane+1. The reference's non-commutative scan
//   combine((a1,c1),(a2,c2)) = (a1+a2, logaddexp(c2, c1+a2))
// is evaluated in closed form: R_u = A~_u + log sum_{k<=u} exp(c_k - A~_k)
// (A~ = prefix sum of a with a_0 := 0; the NEG at u=0 cancels in every
// difference). Cross-lane work = two add-scans + one max-scan, all DPP.
__global__ __launch_bounds__(64) void dp_kernel(
        const float* __restrict__ blank_lp,
        const float* __restrict__ emit_lp,
        const int*   __restrict__ logit_lengths,
        const int*   __restrict__ target_lengths,
        float* __restrict__ nll) {
    const int b    = blockIdx.x;
    const int lane = threadIdx.x;
    const float* blp = blank_lp + b * Tt * UP1;
    const float* elp = emit_lp  + b * Tt * Uu;
    const int tl = logit_lengths[b];
    const int ul = target_lengths[b];
    const int t_idx = tl - 2;   // reference: alpha[(tl-1)-1, ul]

    const int u0 = lane * 2, u1 = u0 + 1;
    const bool v0 = (u0 <= Uu), v1 = (u1 <= Uu);

    // alpha0: inclusive additive scan of h, h[0]=0, h[u]=emit[0][u-1]
    float h0 = (lane > 0 && v0) ? elp[u0 - 1] : 0.0f;
    float h1 = v1 ? elp[u1 - 1] : 0.0f;
    float s = h0 + h1;
    WAVE_SCAN_ADD(s);
    float excl = s - (h0 + h1);
    float rc0 = excl + h0;       // alpha[0][u0]
    float rc1 = excl + h0 + h1;  // alpha[0][u1]

    float cap = NEGV;
    if (t_idx == 0) {
        float w0 = __shfl(rc0, ul >> 1, 64);
        float w1 = __shfl(rc1, ul >> 1, 64);
        cap = (ul & 1) ? w1 : w0;
    }

    // prefetched operands for step t (blank row t-1, emit row t)
    float bl0 = 0.f, bl1 = 0.f, pa0 = 0.f, pa1 = 0.f;
    if (t_idx >= 1) {
        const float* br = blp;              // (t-1)=0
        const float* er = elp + Uu;         // t=1
        bl0 = v0 ? br[u0] : 0.0f;
        bl1 = v1 ? br[u1] : 0.0f;
        pa0 = (lane > 0 && v0) ? er[u0 - 1] : 0.0f;
        pa1 = v1 ? er[u1 - 1] : 0.0f;
    }

    for (int t = 1; t <= t_idx; ++t) {
        float B0 = bl0, B1 = bl1, A0 = pa0, A1 = pa1;
        // prefetch next step (duplicate last step's loads on final iter)
        {
            int tn = (t < t_idx) ? t + 1 : t;
            const float* br = blp + (tn - 1) * UP1;
            const float* er = elp + tn * Uu;
            bl0 = v0 ? br[u0] : 0.0f;
            bl1 = v1 ? br[u1] : 0.0f;
            pa0 = (lane > 0 && v0) ? er[u0 - 1] : 0.0f;
            pa1 = v1 ? er[u1 - 1] : 0.0f;
        }

        float c0 = v0 ? rc0 + B0 : NEGV;
        float c1 = v1 ? rc1 + B1 : NEGV;
        float a0 = A0;   // lane0 slot0: a := 0 (A~ trick); invalid slots: 0
        float a1 = A1;

        // per-lane pair aggregate: left=(a0,c0), right=(a1,c1)
        float sa = a0 + a1;
        float sc = laddexp(c1, c0 + a1);

        // cross-lane scan via exp-trick
        float SA = sa;
        WAVE_SCAN_ADD(SA);                 // inclusive prefix of sa
        float g = sc - SA;
        float gm = g;
        WAVE_SCAN_MAX(gm);
        float m = readlane_f(gm, 63);      // global max of g
        float e = __expf(g - m);
        float P = e;
        WAVE_SCAN_ADD(P);                  // inclusive prefix of e

        rc1 = fmaxf(SA + m + __logf(P), NEGV);          // alpha[t][u1]
        float Px = fmaxf(P - e, 0.0f);                  // exclusive prefix
        float Xc = (SA - sa) + m + __logf(Px);          // R_{lane-1}
        rc0 = (lane == 0) ? c0 : laddexp(c0, Xc + a0);  // alpha[t][u0]

        if (t == t_idx) {
            float w0 = __shfl(rc0, ul >> 1, 64);
            float w1 = __shfl(rc1, ul >> 1, 64);
            cap = (ul & 1) ? w1 : w0;
        }
    }

    if (lane == 0) {
        float ll = cap + blp[t_idx * UP1 + ul];
        nll[b] = -ll;
    }
}

__global__ void mean_kernel(const float* __restrict__ nll, float* __restrict__ out) {
    if (threadIdx.x == 0 && blockIdx.x == 0) {
        float s = 0.0f;
        for (int i = 0; i < Bb; ++i) s += nll[i];
        out[0] = s / (float)Bb;
    }
}

extern "C" void kernel_launch(void* const* d_in, const int* in_sizes, int n_in,
                              void* d_out, int out_size, void* d_ws, size_t ws_size,
                              hipStream_t stream) {
    const float* logits        = (const float*)d_in[0];
    const int*   targets       = (const int*)d_in[1];
    const int*   logit_lengths = (const int*)d_in[2];
    const int*   target_lengths= (const int*)d_in[3];
    float* out = (float*)d_out;

    float* ws       = (float*)d_ws;
    float* blank_lp = ws;                              // B*T*(U+1) = 103424
    float* emit_lp  = blank_lp + Bb * Tt * UP1;        // B*T*U     = 102400
    float* nll      = emit_lp  + Bb * Tt * Uu;         // B         = 8

    const int rows = Bb * Tt * UP1;                    // 103424, divisible by 4
    lse_kernel<<<rows / 4, 256, 0, stream>>>(logits, targets, blank_lp, emit_lp);
    dp_kernel<<<Bb, 64, 0, stream>>>(blank_lp, emit_lp, logit_lengths, target_lengths, nll);
    mean_kernel<<<1, 64, 0, stream>>>(nll, out);
}

// Round 4
// 121.619 us; speedup vs baseline: 3.4818x; 1.3971x over previous
//
#include <hip/hip_runtime.h>

// RNN-T loss forward: B=8, T=128, U=100, V=1024, BLANK=0.
// out = mean_b of -( alpha[tl-2, ul] + blank_lp[tl-2, ul] )
//
// Anti-diagonal DP: alpha[t,u] = logaddexp(alpha[t-1,u]+blank[t-1,u],
//                                          alpha[t,u-1]+emit[t,u-1])
// Cells on diagonal d = t+u depend only on diagonal d-1 (same u: same lane;
// u-1: neighbor lane slot via DPP wave_shr:1). No cross-lane scan at all.

#define NEGV (-1e30f)

constexpr int Bb = 8;
constexpr int Tt = 128;
constexpr int Uu = 100;
constexpr int Vv = 1024;
constexpr int UP1 = Uu + 1;
constexpr int NDIAG = Tt + Uu;   // 228 diagonals (d = 1..228 computed)
constexpr int DROWS = 236;       // rows allocated (prefetch reads up to d=232)
constexpr int DPAD  = 104;       // row pitch in floats (even -> float2 aligned)

__device__ __forceinline__ float laddexp(float x, float y) {
    float m = fmaxf(x, y);
    float d = fabsf(x - y);
    return m + __logf(1.0f + __expf(-d));
}

// lane l receives lane l-1's value (crosses row-of-16 boundaries); lane 0 -> 0
__device__ __forceinline__ float wave_shr1(float x) {
    return __builtin_bit_cast(float, __builtin_amdgcn_update_dpp(
        0, __builtin_bit_cast(int, x), 0x138, 0xf, 0xf, true));
}

__device__ __forceinline__ float readlane_f(float x, int lane) {
    return __builtin_bit_cast(float,
        __builtin_amdgcn_readlane(__builtin_bit_cast(int, x), lane));
}

// Kernel 1: per (b,t,u) row of V=1024 logits compute lse; scatter the two
// needed log-probs into DIAGONAL-major staging:
//   bS[b][d][u]  = blank_lp[t][u]  at d = t+u+1   (cell (d,u) reads blank[t-1][u])
//   eS[b][d][u+1]= emit_lp [t][u]  at d = t+u+1   (cell (d,u') reads emit[t][u'-1])
__global__ __launch_bounds__(256) void lse_kernel(
        const float* __restrict__ logits,
        const int*   __restrict__ targets,
        float* __restrict__ bS,
        float* __restrict__ eS) {
    const int wid  = blockIdx.x * 4 + (threadIdx.x >> 6);   // row index
    const int lane = threadIdx.x & 63;
    const int b   = wid / (Tt * UP1);
    const int rem = wid - b * (Tt * UP1);
    const int t   = rem / UP1;
    const int u   = rem - t * UP1;

    const float* row = logits + (size_t)wid * Vv;
    const float4* r4 = (const float4*)row;
    float4 x0 = r4[lane];
    float4 x1 = r4[lane + 64];
    float4 x2 = r4[lane + 128];
    float4 x3 = r4[lane + 192];

    float m = fmaxf(fmaxf(fmaxf(x0.x, x0.y), fmaxf(x0.z, x0.w)),
                    fmaxf(fmaxf(x1.x, x1.y), fmaxf(x1.z, x1.w)));
    m = fmaxf(m, fmaxf(fmaxf(fmaxf(x2.x, x2.y), fmaxf(x2.z, x2.w)),
                       fmaxf(fmaxf(x3.x, x3.y), fmaxf(x3.z, x3.w))));
    #pragma unroll
    for (int d = 32; d > 0; d >>= 1) m = fmaxf(m, __shfl_xor(m, d, 64));

    float s = __expf(x0.x - m) + __expf(x0.y - m) + __expf(x0.z - m) + __expf(x0.w - m)
            + __expf(x1.x - m) + __expf(x1.y - m) + __expf(x1.z - m) + __expf(x1.w - m)
            + __expf(x2.x - m) + __expf(x2.y - m) + __expf(x2.z - m) + __expf(x2.w - m)
            + __expf(x3.x - m) + __expf(x3.y - m) + __expf(x3.z - m) + __expf(x3.w - m);
    #pragma unroll
    for (int d = 32; d > 0; d >>= 1) s += __shfl_xor(s, d, 64);

    float lse = m + __logf(s);

    if (lane == 0) {
        const int dw = t + u + 1;                       // 1..228
        bS[((size_t)b * DROWS + dw) * DPAD + u] = x0.x - lse;   // row[0] = BLANK
        if (u < Uu) {
            int tgt = targets[b * Uu + u];
            eS[((size_t)b * DROWS + dw) * DPAD + (u + 1)] = row[tgt] - lse;
        }
    }
}

// Kernel 2: fused DP + mean. One 512-thread block; wave w handles batch b=w.
// Lane owns u = 2*lane, 2*lane+1 of the current diagonal. Prefetch FIFO of
// depth 4 (statically named slots; trip count 228 = 4*57, no remainder).
__global__ __launch_bounds__(512) void dp_kernel(
        const float* __restrict__ bS,
        const float* __restrict__ eS,
        const int*   __restrict__ logit_lengths,
        const int*   __restrict__ target_lengths,
        float* __restrict__ out) {
    const int tid  = threadIdx.x;
    const int b    = tid >> 6;
    const int lane = tid & 63;
    const float* bB = bS + (size_t)b * DROWS * DPAD;
    const float* eB = eS + (size_t)b * DROWS * DPAD;
    const int tl = logit_lengths[b];
    const int ul = target_lengths[b];
    const int t_idx = tl - 2;          // reference reads alpha[tl-2][ul]
    const int dcap  = t_idx + ul;      // diagonal of the readout cell

    const int u0 = lane * 2, u1 = u0 + 1;

    float aP0 = (lane == 0) ? 0.0f : NEGV;   // alpha diag 0: only (0,0)=0
    float aP1 = NEGV;
    float cap = (dcap == 0) ? 0.0f : NEGV;

    auto ldb2 = [&](int d) -> float2 {
        return *(const float2*)(bB + (size_t)d * DPAD + u0);
    };
    auto lde2 = [&](int d) -> float2 {
        return *(const float2*)(eB + (size_t)d * DPAD + u0);
    };

    float2 B0 = ldb2(1), B1 = ldb2(2), B2 = ldb2(3), B3 = ldb2(4);
    float2 E0 = lde2(1), E1 = lde2(2), E2 = lde2(3), E3 = lde2(4);

    // Cell (d,u), t=d-u:  blank-term valid iff t>=1 (u<d); emit-term valid
    // iff u>=1. Frontier cell u==d gets exactly the emit chain (laddexp with
    // NEGV is exact). Cells with u>d or t>127 are garbage but finite, and
    // never feed a valid cell.
#define STEP(dv, Bq, Eq) do {                                          \
        float sh  = wave_shr1(aP1);                                    \
        float t1b = (u1 < (dv)) ? aP1 + Bq.y : NEGV;                   \
        float t1e = aP0 + Eq.y;                                        \
        float t0b = (u0 < (dv)) ? aP0 + Bq.x : NEGV;                   \
        float t0e = (lane >= 1) ? sh + Eq.x : NEGV;                    \
        float n1 = laddexp(t1b, t1e);                                  \
        float n0 = laddexp(t0b, t0e);                                  \
        Bq = ldb2((dv) + 4); Eq = lde2((dv) + 4);                      \
        aP0 = n0; aP1 = n1;                                            \
        if ((dv) == dcap) {                                            \
            float w0 = readlane_f(n0, ul >> 1);                        \
            float w1 = readlane_f(n1, ul >> 1);                        \
            cap = (ul & 1) ? w1 : w0;                                  \
        }                                                              \
    } while (0)

    for (int dd = 0; dd < NDIAG / 4; ++dd) {
        int d = dd * 4 + 1;
        STEP(d,     B0, E0);
        STEP(d + 1, B1, E1);
        STEP(d + 2, B2, E2);
        STEP(d + 3, B3, E3);
    }
#undef STEP

    __shared__ float s_nll[Bb];
    if (lane == 0) {
        float ll = cap + bB[(size_t)(dcap + 1) * DPAD + ul];  // + blank[t_idx][ul]
        s_nll[b] = -ll;
    }
    __syncthreads();
    if (tid == 0) {
        float s = 0.0f;
        for (int i = 0; i < Bb; ++i) s += s_nll[i];
        out[0] = s / (float)Bb;
    }
}

extern "C" void kernel_launch(void* const* d_in, const int* in_sizes, int n_in,
                              void* d_out, int out_size, void* d_ws, size_t ws_size,
                              hipStream_t stream) {
    const float* logits         = (const float*)d_in[0];
    const int*   targets        = (const int*)d_in[1];
    const int*   logit_lengths  = (const int*)d_in[2];
    const int*   target_lengths = (const int*)d_in[3];
    float* out = (float*)d_out;

    float* ws = (float*)d_ws;
    float* bS = ws;                                     // 8*236*104 floats
    float* eS = bS + (size_t)Bb * DROWS * DPAD;         // 8*236*104 floats

    const int rows = Bb * Tt * UP1;                     // 103424, divisible by 4
    lse_kernel<<<rows / 4, 256, 0, stream>>>(logits, targets, bS, eS);
    dp_kernel<<<1, 512, 0, stream>>>(bS, eS, logit_lengths, target_lengths, out);
}

// Round 5
// 109.152 us; speedup vs baseline: 3.8795x; 1.1142x over previous
//
#include <hip/hip_runtime.h>

// RNN-T loss forward: B=8, T=128, U=100, V=1024, BLANK=0.
// out = mean_b of -( alpha[tl-2, ul] + blank_lp[tl-2, ul] )
//
// Anti-diagonal DP: alpha[t,u] = logaddexp(alpha[t-1,u]+blank[t-1,u],
//                                          alpha[t,u-1]+emit[t,u-1])
// Diagonal d = t+u depends only on diagonal d-1 (same u: same lane slot;
// u-1: neighbor slot via DPP wave_shr:1). No cross-lane scan.

#define NEGV (-1e30f)

constexpr int Bb = 8;
constexpr int Tt = 128;
constexpr int Uu = 100;
constexpr int Vv = 1024;
constexpr int UP1 = Uu + 1;
constexpr int NSTEP = 232;       // diagonals 1..232 (229..232 harmless garbage)
constexpr int DROWS = 244;       // prefetch reads up to row 240
constexpr int DPAD  = 104;       // row pitch in floats (float2-aligned)

__device__ __forceinline__ float laddexp(float x, float y) {
    float m = fmaxf(x, y);
    float d = fabsf(x - y);
    return m + __logf(1.0f + __expf(-d));
}

// lane l receives lane l-1's value (crosses row-of-16 boundaries); lane 0 -> 0
__device__ __forceinline__ float wave_shr1(float x) {
    return __builtin_bit_cast(float, __builtin_amdgcn_update_dpp(
        0, __builtin_bit_cast(int, x), 0x138, 0xf, 0xf, true));
}

__device__ __forceinline__ float readlane_f(float x, int lane) {
    return __builtin_bit_cast(float,
        __builtin_amdgcn_readlane(__builtin_bit_cast(int, x), lane));
}

// Kernel 1: per (b,t,u) row of V=1024 logits compute lse; scatter the two
// needed log-probs into DIAGONAL-major staging:
//   bS[b][d][u]   = blank_lp[t][u] at d = t+u+1  (cell (d,u) reads blank[t-1][u])
//   eS[b][d][u+1] = emit_lp [t][u] at d = t+u+1  (cell (d,u') reads emit[t][u'-1])
__global__ __launch_bounds__(256) void lse_kernel(
        const float* __restrict__ logits,
        const int*   __restrict__ targets,
        float* __restrict__ bS,
        float* __restrict__ eS) {
    const int wid  = blockIdx.x * 4 + (threadIdx.x >> 6);   // row index
    const int lane = threadIdx.x & 63;
    const int b   = wid / (Tt * UP1);
    const int rem = wid - b * (Tt * UP1);
    const int t   = rem / UP1;
    const int u   = rem - t * UP1;

    const float* row = logits + (size_t)wid * Vv;
    const float4* r4 = (const float4*)row;
    float4 x0 = r4[lane];
    float4 x1 = r4[lane + 64];
    float4 x2 = r4[lane + 128];
    float4 x3 = r4[lane + 192];

    float m = fmaxf(fmaxf(fmaxf(x0.x, x0.y), fmaxf(x0.z, x0.w)),
                    fmaxf(fmaxf(x1.x, x1.y), fmaxf(x1.z, x1.w)));
    m = fmaxf(m, fmaxf(fmaxf(fmaxf(x2.x, x2.y), fmaxf(x2.z, x2.w)),
                       fmaxf(fmaxf(x3.x, x3.y), fmaxf(x3.z, x3.w))));
    #pragma unroll
    for (int d = 32; d > 0; d >>= 1) m = fmaxf(m, __shfl_xor(m, d, 64));

    float s = __expf(x0.x - m) + __expf(x0.y - m) + __expf(x0.z - m) + __expf(x0.w - m)
            + __expf(x1.x - m) + __expf(x1.y - m) + __expf(x1.z - m) + __expf(x1.w - m)
            + __expf(x2.x - m) + __expf(x2.y - m) + __expf(x2.z - m) + __expf(x2.w - m)
            + __expf(x3.x - m) + __expf(x3.y - m) + __expf(x3.z - m) + __expf(x3.w - m);
    #pragma unroll
    for (int d = 32; d > 0; d >>= 1) s += __shfl_xor(s, d, 64);

    float lse = m + __logf(s);

    if (lane == 0) {
        const int dw = t + u + 1;                       // 1..228
        bS[((size_t)b * DROWS + dw) * DPAD + u] = x0.x - lse;   // row[0] = BLANK
        if (u < Uu) {
            int tgt = targets[b * Uu + u];
            eS[((size_t)b * DROWS + dw) * DPAD + (u + 1)] = row[tgt] - lse;
        }
    }
}

// Kernel 2: one 64-lane block per batch element (own CU, full issue rate).
// Lane owns u = 2*lane, 2*lane+1. Depth-8 named-slot register FIFO
// (distance-8 prefetch covers L2/L3 latency); running pointers, no per-step
// index math. Cells with u>d or t>127 are finite garbage, never read.
__global__ __launch_bounds__(64) void dp_kernel(
        const float* __restrict__ bS,
        const float* __restrict__ eS,
        const int*   __restrict__ logit_lengths,
        const int*   __restrict__ target_lengths,
        float* __restrict__ nll) {
    const int b    = blockIdx.x;
    const int lane = threadIdx.x;
    const float* bB = bS + (size_t)b * DROWS * DPAD;
    const float* eB = eS + (size_t)b * DROWS * DPAD;
    const int tl = logit_lengths[b];
    const int ul = target_lengths[b];
    const int t_idx = tl - 2;          // reference reads alpha[tl-2][ul]
    const int dcap  = t_idx + ul;      // diagonal of the readout cell

    const int u0 = lane * 2, u1 = u0 + 1;

    float aP0 = (lane == 0) ? 0.0f : NEGV;   // alpha diag 0: only (0,0)=0
    float aP1 = NEGV;
    float cap = (dcap == 0) ? 0.0f : NEGV;

    const float* pb = bB + DPAD + u0;        // row d=1, this lane's pair
    const float* pe = eB + DPAD + u0;

    float2 B0 = *(const float2*)(pb + 0*DPAD), E0 = *(const float2*)(pe + 0*DPAD);
    float2 B1 = *(const float2*)(pb + 1*DPAD), E1 = *(const float2*)(pe + 1*DPAD);
    float2 B2 = *(const float2*)(pb + 2*DPAD), E2 = *(const float2*)(pe + 2*DPAD);
    float2 B3 = *(const float2*)(pb + 3*DPAD), E3 = *(const float2*)(pe + 3*DPAD);
    float2 B4 = *(const float2*)(pb + 4*DPAD), E4 = *(const float2*)(pe + 4*DPAD);
    float2 B5 = *(const float2*)(pb + 5*DPAD), E5 = *(const float2*)(pe + 5*DPAD);
    float2 B6 = *(const float2*)(pb + 6*DPAD), E6 = *(const float2*)(pe + 6*DPAD);
    float2 B7 = *(const float2*)(pb + 7*DPAD), E7 = *(const float2*)(pe + 7*DPAD);

    const float* pbL = pb + 8*DPAD;          // next row to prefetch (d=9)
    const float* peL = pe + 8*DPAD;

    int dv = 1;
#define STEP(Bq, Eq) do {                                              \
        float sh  = wave_shr1(aP1);                                    \
        float t1b = (u1 < dv) ? aP1 + Bq.y : NEGV;                     \
        float t1e = aP0 + Eq.y;                                        \
        float t0b = (u0 < dv) ? aP0 + Bq.x : NEGV;                     \
        float t0e = (lane >= 1) ? sh + Eq.x : NEGV;                    \
        float n1 = laddexp(t1b, t1e);                                  \
        float n0 = laddexp(t0b, t0e);                                  \
        Bq = *(const float2*)pbL; Eq = *(const float2*)peL;            \
        pbL += DPAD; peL += DPAD;                                      \
        aP0 = n0; aP1 = n1;                                            \
        if (dv == dcap) {                                              \
            float w0 = readlane_f(n0, ul >> 1);                        \
            float w1 = readlane_f(n1, ul >> 1);                        \
            cap = (ul & 1) ? w1 : w0;                                  \
        }                                                              \
        ++dv;                                                          \
    } while (0)

    for (int it = 0; it < NSTEP / 8; ++it) {   // 29 iterations x 8 diagonals
        STEP(B0, E0); STEP(B1, E1); STEP(B2, E2); STEP(B3, E3);
        STEP(B4, E4); STEP(B5, E5); STEP(B6, E6); STEP(B7, E7);
    }
#undef STEP

    if (lane == 0) {
        float ll = cap + bB[(size_t)(dcap + 1) * DPAD + ul];  // + blank[t_idx][ul]
        nll[b] = -ll;
    }
}

__global__ void mean_kernel(const float* __restrict__ nll, float* __restrict__ out) {
    if (threadIdx.x == 0 && blockIdx.x == 0) {
        float s = 0.0f;
        for (int i = 0; i < Bb; ++i) s += nll[i];
        out[0] = s / (float)Bb;
    }
}

extern "C" void kernel_launch(void* const* d_in, const int* in_sizes, int n_in,
                              void* d_out, int out_size, void* d_ws, size_t ws_size,
                              hipStream_t stream) {
    const float* logits         = (const float*)d_in[0];
    const int*   targets        = (const int*)d_in[1];
    const int*   logit_lengths  = (const int*)d_in[2];
    const int*   target_lengths = (const int*)d_in[3];
    float* out = (float*)d_out;

    float* ws = (float*)d_ws;
    float* bS = ws;                                     // 8*244*104 floats
    float* eS = bS + (size_t)Bb * DROWS * DPAD;
    float* nll = eS + (size_t)Bb * DROWS * DPAD;        // 8 floats

    const int rows = Bb * Tt * UP1;                     // 103424, divisible by 4
    lse_kernel<<<rows / 4, 256, 0, stream>>>(logits, targets, bS, eS);
    dp_kernel<<<Bb, 64, 0, stream>>>(bS, eS, logit_lengths, target_lengths, nll);
    mean_kernel<<<1, 64, 0, stream>>>(nll, out);
}

// Round 7
// 106.323 us; speedup vs baseline: 3.9827x; 1.0266x over previous
//
#include <hip/hip_runtime.h>

// RNN-T loss forward: B=8, T=128, U=100, V=1024, BLANK=0.
// out = mean_b of -( alpha[tl-2, ul] + blank_lp[tl-2, ul] )
//
// Anti-diagonal DP: alpha[t,u] = logaddexp(alpha[t-1,u]+blank[t-1,u],
//                                          alpha[t,u-1]+emit[t,u-1])
// Diagonal d = t+u depends only on diagonal d-1 (same u: same lane slot;
// u-1: neighbor slot via DPP wave_shr:1).
// dp_kernel: one block per batch, 2 waves: wave1 streams staging into an LDS
// double-buffer (global-load latency off the critical path), wave0 runs the DP.

#define NEGV (-1e30f)

constexpr int Bb = 8;
constexpr int Tt = 128;
constexpr int Uu = 100;
constexpr int Vv = 1024;
constexpr int UP1 = Uu + 1;
constexpr int DROWS = 244;       // staging rows (d up to 232 + lane spill)
constexpr int DPAD  = 104;       // staging row pitch in floats
constexpr int CHUNK = 8;         // diagonals per chunk
constexpr int LPITCH = 128;      // LDS row pitch in floats

__device__ __forceinline__ float laddexp(float x, float y) {
    float m = fmaxf(x, y);
    float d = fabsf(x - y);
    return m + __logf(1.0f + __expf(-d));
}

// lane l receives lane l-1's value; lane 0 -> 0
__device__ __forceinline__ float wave_shr1(float x) {
    return __builtin_bit_cast(float, __builtin_amdgcn_update_dpp(
        0, __builtin_bit_cast(int, x), 0x138, 0xf, 0xf, true));
}

__device__ __forceinline__ float readlane_f(float x, int lane) {
    return __builtin_bit_cast(float,
        __builtin_amdgcn_readlane(__builtin_bit_cast(int, x), lane));
}

// Kernel 1: per (b,t,u) row of V=1024 logits compute lse; scatter the two
// needed log-probs into diagonal-major staging:
//   bS[b][d][u]   = blank_lp[t][u] at d = t+u+1  (cell (d,u) reads blank[t-1][u])
//   eS[b][d][u+1] = emit_lp [t][u] at d = t+u+1  (cell (d,u') reads emit[t][u'-1])
__global__ __launch_bounds__(256) void lse_kernel(
        const float* __restrict__ logits,
        const int*   __restrict__ targets,
        float* __restrict__ bS,
        float* __restrict__ eS) {
    const int wid  = blockIdx.x * 4 + (threadIdx.x >> 6);   // row index
    const int lane = threadIdx.x & 63;
    const int b   = wid / (Tt * UP1);
    const int rem = wid - b * (Tt * UP1);
    const int t   = rem / UP1;
    const int u   = rem - t * UP1;

    const float* row = logits + (size_t)wid * Vv;
    const float4* r4 = (const float4*)row;
    float4 x0 = r4[lane];
    float4 x1 = r4[lane + 64];
    float4 x2 = r4[lane + 128];
    float4 x3 = r4[lane + 192];

    float m = fmaxf(fmaxf(fmaxf(x0.x, x0.y), fmaxf(x0.z, x0.w)),
                    fmaxf(fmaxf(x1.x, x1.y), fmaxf(x1.z, x1.w)));
    m = fmaxf(m, fmaxf(fmaxf(fmaxf(x2.x, x2.y), fmaxf(x2.z, x2.w)),
                       fmaxf(fmaxf(x3.x, x3.y), fmaxf(x3.z, x3.w))));
    #pragma unroll
    for (int d = 32; d > 0; d >>= 1) m = fmaxf(m, __shfl_xor(m, d, 64));

    float s = __expf(x0.x - m) + __expf(x0.y - m) + __expf(x0.z - m) + __expf(x0.w - m)
            + __expf(x1.x - m) + __expf(x1.y - m) + __expf(x1.z - m) + __expf(x1.w - m)
            + __expf(x2.x - m) + __expf(x2.y - m) + __expf(x2.z - m) + __expf(x2.w - m)
            + __expf(x3.x - m) + __expf(x3.y - m) + __expf(x3.z - m) + __expf(x3.w - m);
    #pragma unroll
    for (int d = 32; d > 0; d >>= 1) s += __shfl_xor(s, d, 64);

    float lse = m + __logf(s);

    if (lane == 0) {
        const int dw = t + u + 1;                       // 1..228
        bS[((size_t)b * DROWS + dw) * DPAD + u] = x0.x - lse;   // row[0] = BLANK
        if (u < Uu) {
            int tgt = targets[b * Uu + u];
            eS[((size_t)b * DROWS + dw) * DPAD + (u + 1)] = row[tgt] - lse;
        }
    }
}

// Kernel 2: one 128-thread block per batch. Wave 0 = DP consumer (from LDS),
// wave 1 = producer (global -> LDS double-buffer, 2 register sets deep).
__global__ __launch_bounds__(128) void dp_kernel(
        const float* __restrict__ bS,
        const float* __restrict__ eS,
        const int*   __restrict__ logit_lengths,
        const int*   __restrict__ target_lengths,
        float* __restrict__ nll) {
    const int b    = blockIdx.x;
    const int tid  = threadIdx.x;
    const int wv   = tid >> 6;          // 0 = consumer, 1 = producer
    const int lane = tid & 63;
    const float* bB = bS + (size_t)b * DROWS * DPAD;
    const float* eB = eS + (size_t)b * DROWS * DPAD;
    const int tl = logit_lengths[b];
    const int ul = target_lengths[b];
    const int t_idx = tl - 2;           // reference reads alpha[tl-2][ul]
    const int dcap  = t_idx + ul;       // diagonal of the readout cell

    __shared__ float ringB[2][CHUNK][LPITCH];
    __shared__ float ringE[2][CHUNK][LPITCH];

    // consumer state
    const int u0 = lane * 2, u1 = u0 + 1;
    float aP0 = (lane == 0) ? 0.0f : NEGV;   // alpha diag 0: only (0,0)=0
    float aP1 = NEGV;
    float cap = (dcap == 0) ? 0.0f : NEGV;

    // producer state: two register sets (chunk k lives in set k&1)
    float2 LAb[CHUNK], LAe[CHUNK], LBb[CHUNK], LBe[CHUNK];

#define PLOAD(SETb, SETe, ck) do {                                           \
        const float* _pb = bB + (size_t)((ck) * CHUNK + 1) * DPAD + lane * 2;\
        const float* _pe = eB + (size_t)((ck) * CHUNK + 1) * DPAD + lane * 2;\
        _Pragma("unroll")                                                    \
        for (int r = 0; r < CHUNK; ++r) {                                    \
            SETb[r] = *(const float2*)(_pb + r * DPAD);                      \
            SETe[r] = *(const float2*)(_pe + r * DPAD);                      \
        }                                                                    \
    } while (0)

#define PWRITE(SETb, SETe, slot) do {                                        \
        _Pragma("unroll")                                                    \
        for (int r = 0; r < CHUNK; ++r) {                                    \
            *(float2*)&ringB[slot][r][lane * 2] = SETb[r];                   \
            *(float2*)&ringE[slot][r][lane * 2] = SETe[r];                   \
        }                                                                    \
    } while (0)

    // consumer: process chunk cc from LDS slot; diagonals cc*8+1 .. cc*8+8
#define CCHUNK(cc, slot) do {                                                \
        float2 Bv[CHUNK], Ev[CHUNK];                                         \
        _Pragma("unroll")                                                    \
        for (int r = 0; r < CHUNK; ++r) {                                    \
            Bv[r] = *(const float2*)&ringB[slot][r][u0];                     \
            Ev[r] = *(const float2*)&ringE[slot][r][u0];                     \
        }                                                                    \
        _Pragma("unroll")                                                    \
        for (int r = 0; r < CHUNK; ++r) {                                    \
            const int dv = (cc) * CHUNK + 1 + r;                             \
            float sh  = wave_shr1(aP1);                                      \
            float t1b = (u1 < dv) ? aP1 + Bv[r].y : NEGV;                    \
            float t1e = aP0 + Ev[r].y;                                       \
            float t0b = (u0 < dv) ? aP0 + Bv[r].x : NEGV;                    \
            float t0e = (lane >= 1) ? sh + Ev[r].x : NEGV;                   \
            float n1 = laddexp(t1b, t1e);                                    \
            float n0 = laddexp(t0b, t0e);                                    \
            aP0 = n0; aP1 = n1;                                              \
            if (dv == dcap) {                                                \
                float w0 = readlane_f(n0, ul >> 1);                          \
                float w1 = readlane_f(n1, ul >> 1);                          \
                cap = (ul & 1) ? w1 : w0;                                    \
            }                                                                \
        }                                                                    \
    } while (0)

    // prologue: producer loads chunks 0,1 and writes chunk 0 to slot 0
    if (wv == 1) {
        PLOAD(LAb, LAe, 0);
        PLOAD(LBb, LBe, 1);
        PWRITE(LAb, LAe, 0);
    }
    __syncthreads();

    // main: 14 x (even half, odd half); consumer handles chunks 0..27
    for (int c2 = 0; c2 < 14; ++c2) {
        const int c = c2 * 2;
        // even half: consumer chunk c (slot 0); producer: load c+2 -> setA,
        // write c+1 (setB) -> slot 1
        if (wv == 1) {
            PLOAD(LAb, LAe, c + 2);
            PWRITE(LBb, LBe, 1);
        } else {
            CCHUNK(c, 0);
        }
        __syncthreads();
        // odd half: consumer chunk c+1 (slot 1); producer: load c+3 -> setB
        // (skip when past end), write c+2 (setA) -> slot 0
        if (wv == 1) {
            if (c2 < 13) PLOAD(LBb, LBe, c + 3);
            PWRITE(LAb, LAe, 0);
        } else {
            CCHUNK(c + 1, 1);
        }
        __syncthreads();
    }
    // final chunk 28 (slot 0), consumer only
    if (wv == 0) {
        CCHUNK(28, 0);
        if (lane == 0) {
            float ll = cap + bB[(size_t)(dcap + 1) * DPAD + ul]; // + blank[t_idx][ul]
            nll[b] = -ll;
        }
    }
#undef PLOAD
#undef PWRITE
#undef CCHUNK
}

__global__ void mean_kernel(const float* __restrict__ nll, float* __restrict__ out) {
    if (threadIdx.x == 0 && blockIdx.x == 0) {
        float s = 0.0f;
        for (int i = 0; i < Bb; ++i) s += nll[i];
        out[0] = s / (float)Bb;
    }
}

extern "C" void kernel_launch(void* const* d_in, const int* in_sizes, int n_in,
                              void* d_out, int out_size, void* d_ws, size_t ws_size,
                              hipStream_t stream) {
    const float* logits         = (const float*)d_in[0];
    const int*   targets        = (const int*)d_in[1];
    const int*   logit_lengths  = (const int*)d_in[2];
    const int*   target_lengths = (const int*)d_in[3];
    float* out = (float*)d_out;

    float* ws  = (float*)d_ws;
    float* bS  = ws;                                    // 8*244*104 floats
    float* eS  = bS + (size_t)Bb * DROWS * DPAD;
    float* nll = eS + (size_t)Bb * DROWS * DPAD;        // 8 floats

    const int rows = Bb * Tt * UP1;                     // 103424, divisible by 4
    lse_kernel<<<rows / 4, 256, 0, stream>>>(logits, targets, bS, eS);
    dp_kernel<<<Bb, 128, 0, stream>>>(bS, eS, logit_lengths, target_lengths, nll);
    mean_kernel<<<1, 64, 0, stream>>>(nll, out);
}